// Round 4
// baseline (712.522 us; speedup 1.0000x reference)
//
#include <hip/hip_runtime.h>
#include <hip/hip_bf16.h>

// VGAE forward, MI355X. Gather-based GCN; bf16 storage for all gathered operands.
constexpr int N_ = 50000;
constexpr int E_ = 1600000;
constexpr int D_ = 128;   // embedding_dim == hidden_dim
constexpr int O_ = 64;    // out_embedding_dim
constexpr int NNZ_ = 16;
constexpr int V_ = 100000;

static __device__ __forceinline__ unsigned short f2bf(float f) {
    __hip_bfloat16 h = __float2bfloat16(f);
    return __builtin_bit_cast(unsigned short, h);
}
static __device__ __forceinline__ float blo(unsigned int u) { return __uint_as_float(u << 16); }
static __device__ __forceinline__ float bhi(unsigned int u) { return __uint_as_float(u & 0xffff0000u); }
static __device__ __forceinline__ float4 fma4(float s, float4 a, float4 b) {
    return make_float4(fmaf(s, a.x, b.x), fmaf(s, a.y, b.y),
                       fmaf(s, a.z, b.z), fmaf(s, a.w, b.w));
}

// ---------------------------------------------------------------------------
// 0. Convert fp32 emb table [V][128] -> bf16 (packed u32 pairs). 8 floats/thread.
// ---------------------------------------------------------------------------
__global__ __launch_bounds__(256) void k_cvt(const float* __restrict__ emb,
                                             unsigned int* __restrict__ emb_bf) {
    int t = blockIdx.x * blockDim.x + threadIdx.x;      // 1.6M threads
    if (t >= V_ * D_ / 8) return;
    float4 a = ((const float4*)emb)[t * 2];
    float4 b = ((const float4*)emb)[t * 2 + 1];
    uint4 o;
    o.x = (unsigned int)f2bf(a.x) | ((unsigned int)f2bf(a.y) << 16);
    o.y = (unsigned int)f2bf(a.z) | ((unsigned int)f2bf(a.w) << 16);
    o.z = (unsigned int)f2bf(b.x) | ((unsigned int)f2bf(b.y) << 16);
    o.w = (unsigned int)f2bf(b.z) | ((unsigned int)f2bf(b.w) << 16);
    ((uint4*)emb_bf)[t] = o;
}

// ---------------------------------------------------------------------------
// 1. EmbeddingBag(sum) + L2 normalize from bf16 table. One wave per node.
//    Lane owns dims (2l, 2l+1) -> one packed u32 per lane (256B per row).
// ---------------------------------------------------------------------------
__global__ __launch_bounds__(256) void k_embed(const int* __restrict__ fi,
                                               const float* __restrict__ fw,
                                               const unsigned int* __restrict__ emb_bf,
                                               unsigned int* __restrict__ x) {
    int n = blockIdx.x * 4 + (threadIdx.x >> 6);
    if (n >= N_) return;
    int lane = threadIdx.x & 63;
    float a0 = 0.f, a1 = 0.f;
    int base = n * NNZ_;
#pragma unroll
    for (int j = 0; j < NNZ_; ++j) {
        int idx  = fi[base + j];
        float w  = fw[base + j];
        unsigned int r = emb_bf[(size_t)idx * 64 + lane];
        a0 = fmaf(w, blo(r), a0);
        a1 = fmaf(w, bhi(r), a1);
    }
    float ss = a0 * a0 + a1 * a1;
#pragma unroll
    for (int o = 32; o; o >>= 1) ss += __shfl_xor(ss, o);
    float sc = 1.0f / fmaxf(sqrtf(ss), 1e-12f);
    x[(size_t)n * 64 + lane] =
        (unsigned int)f2bf(a0 * sc) | ((unsigned int)f2bf(a1 * sc) << 16);
}

// ---------------------------------------------------------------------------
// 2. In-degree histogram + normalization factors
// ---------------------------------------------------------------------------
__global__ __launch_bounds__(256) void k_degcnt(const int* __restrict__ dst,
                                                int* __restrict__ cnt) {
    int e = blockIdx.x * blockDim.x + threadIdx.x;
    if (e < E_) atomicAdd(&cnt[dst[e]], 1);
}

__global__ __launch_bounds__(256) void k_degnorm(const int* __restrict__ cnt,
                                                 float* __restrict__ disq,
                                                 float* __restrict__ dinv) {
    int n = blockIdx.x * blockDim.x + threadIdx.x;
    if (n < N_) {
        float deg = 1.0f + (float)cnt[n];
        disq[n] = rsqrtf(deg);
        dinv[n] = 1.0f / deg;
    }
}

// ---------------------------------------------------------------------------
// 3. Exclusive scan of cnt -> row_start[N+1]; also emits cursor = row_start copy.
// ---------------------------------------------------------------------------
__global__ __launch_bounds__(256) void k_scan(const int* __restrict__ cnt,
                                              int* __restrict__ row_start,
                                              int* __restrict__ cursor) {
    __shared__ int sums[256];
    const int chunk = (N_ + 255) / 256;
    int t = threadIdx.x;
    int begin = t * chunk;
    int end   = begin + chunk; if (end > N_) end = N_;
    int s = 0;
    for (int i = begin; i < end; ++i) s += cnt[i];
    sums[t] = s;
    __syncthreads();
    for (int o = 1; o < 256; o <<= 1) {
        int v = (t >= o) ? sums[t - o] : 0;
        __syncthreads();
        sums[t] += v;
        __syncthreads();
    }
    int run = t ? sums[t - 1] : 0;
    for (int i = begin; i < end; ++i) {
        row_start[i] = run; cursor[i] = run; run += cnt[i];
    }
    if (t == 255) row_start[N_] = run;
}

// ---------------------------------------------------------------------------
// 4. CSR fill by dst: single 4B scatter per edge, atomic cursor gives position.
// ---------------------------------------------------------------------------
__global__ __launch_bounds__(256) void k_fill(const int* __restrict__ src,
                                              const int* __restrict__ dst,
                                              int* __restrict__ cursor,
                                              int* __restrict__ sorted_src) {
    int e = blockIdx.x * blockDim.x + threadIdx.x;
    if (e >= E_) return;
    int pos = atomicAdd(&cursor[dst[e]], 1);
    sorted_src[pos] = src[e];
}

// ---------------------------------------------------------------------------
// 5. Gather aggregation from bf16 rows:
//    agg[n] = disq[n] * sum_j disq[s_j]*v[s_j]  +  dinv[n]*v[n]
//    One wave per node; lane reads one u32 (2 bf16) = 256B per row.
// ---------------------------------------------------------------------------
__global__ __launch_bounds__(256) void k_gather(const int* __restrict__ row_start,
                                                const int* __restrict__ sorted_src,
                                                const float* __restrict__ disq,
                                                const float* __restrict__ dinv,
                                                const unsigned int* __restrict__ v,
                                                float* __restrict__ agg) {
    int n = blockIdx.x * 4 + (threadIdx.x >> 6);
    if (n >= N_) return;
    int lane = threadIdx.x & 63;
    int beg = row_start[n], end = row_start[n + 1];
    float ax = 0.f, ay = 0.f;
    int j = beg;
    for (; j + 7 < end; j += 8) {
        int s0 = sorted_src[j],     s1 = sorted_src[j + 1];
        int s2 = sorted_src[j + 2], s3 = sorted_src[j + 3];
        int s4 = sorted_src[j + 4], s5 = sorted_src[j + 5];
        int s6 = sorted_src[j + 6], s7 = sorted_src[j + 7];
        float w0 = disq[s0], w1 = disq[s1], w2 = disq[s2], w3 = disq[s3];
        float w4 = disq[s4], w5 = disq[s5], w6 = disq[s6], w7 = disq[s7];
        unsigned int b0 = v[(size_t)s0 * 64 + lane];
        unsigned int b1 = v[(size_t)s1 * 64 + lane];
        unsigned int b2 = v[(size_t)s2 * 64 + lane];
        unsigned int b3 = v[(size_t)s3 * 64 + lane];
        unsigned int b4 = v[(size_t)s4 * 64 + lane];
        unsigned int b5 = v[(size_t)s5 * 64 + lane];
        unsigned int b6 = v[(size_t)s6 * 64 + lane];
        unsigned int b7 = v[(size_t)s7 * 64 + lane];
        ax = fmaf(w0, blo(b0), ax); ay = fmaf(w0, bhi(b0), ay);
        ax = fmaf(w1, blo(b1), ax); ay = fmaf(w1, bhi(b1), ay);
        ax = fmaf(w2, blo(b2), ax); ay = fmaf(w2, bhi(b2), ay);
        ax = fmaf(w3, blo(b3), ax); ay = fmaf(w3, bhi(b3), ay);
        ax = fmaf(w4, blo(b4), ax); ay = fmaf(w4, bhi(b4), ay);
        ax = fmaf(w5, blo(b5), ax); ay = fmaf(w5, bhi(b5), ay);
        ax = fmaf(w6, blo(b6), ax); ay = fmaf(w6, bhi(b6), ay);
        ax = fmaf(w7, blo(b7), ax); ay = fmaf(w7, bhi(b7), ay);
    }
    for (; j < end; ++j) {
        int s = sorted_src[j];
        float w = disq[s];
        unsigned int b = v[(size_t)s * 64 + lane];
        ax = fmaf(w, blo(b), ax); ay = fmaf(w, bhi(b), ay);
    }
    float dq = disq[n], di = dinv[n];
    unsigned int bs = v[(size_t)n * 64 + lane];
    ax = fmaf(di, blo(bs), ax * dq);
    ay = fmaf(di, bhi(bs), ay * dq);
    ((float2*)agg)[(size_t)n * 64 + lane] = make_float2(ax, ay);
}

// ---------------------------------------------------------------------------
// 6. Register-blocked GEMM: h = relu(agg @ W1 + b1), bf16 output.
// ---------------------------------------------------------------------------
__global__ __launch_bounds__(256, 2) void k_gemm_relu(const float* __restrict__ u,
                                                      const float* __restrict__ W,
                                                      const float* __restrict__ b,
                                                      unsigned short* __restrict__ hout) {
    __shared__ float lw[D_ * D_];     // 64 KiB
    __shared__ float lu[32 * D_];     // 16 KiB
    int tid = threadIdx.x;
    for (int t = tid; t < D_ * D_ / 4; t += 256)
        ((float4*)lw)[t] = ((const float4*)W)[t];

    int l  = tid & 31;
    int rl = ((tid >> 6) << 3) + (((tid >> 5) & 1) << 2);   // wave*8 + half*4
    float4 bb = ((const float4*)b)[l];

    for (int tile = blockIdx.x; tile * 32 < N_; tile += gridDim.x) {
        int row0 = tile * 32;
        __syncthreads();
#pragma unroll
        for (int i = 0; i < 4; ++i) {
            int flat = i * 256 + tid;
            int r = flat >> 5, c4 = flat & 31;
            int gr = row0 + r;
            ((float4*)lu)[flat] = (gr < N_) ? ((const float4*)u)[(size_t)gr * 32 + c4]
                                            : make_float4(0.f, 0.f, 0.f, 0.f);
        }
        __syncthreads();
        float4 a0 = {0,0,0,0}, a1 = {0,0,0,0}, a2 = {0,0,0,0}, a3 = {0,0,0,0};
#pragma unroll 4
        for (int k4 = 0; k4 < 32; ++k4) {
            int k = k4 * 4;
            float4 w0 = ((const float4*)(lw + (k + 0) * D_))[l];
            float4 w1 = ((const float4*)(lw + (k + 1) * D_))[l];
            float4 w2 = ((const float4*)(lw + (k + 2) * D_))[l];
            float4 w3 = ((const float4*)(lw + (k + 3) * D_))[l];
            float4 u0 = ((const float4*)(lu + (rl + 0) * D_))[k4];
            float4 u1 = ((const float4*)(lu + (rl + 1) * D_))[k4];
            float4 u2 = ((const float4*)(lu + (rl + 2) * D_))[k4];
            float4 u3 = ((const float4*)(lu + (rl + 3) * D_))[k4];
            a0 = fma4(u0.x, w0, fma4(u0.y, w1, fma4(u0.z, w2, fma4(u0.w, w3, a0))));
            a1 = fma4(u1.x, w0, fma4(u1.y, w1, fma4(u1.z, w2, fma4(u1.w, w3, a1))));
            a2 = fma4(u2.x, w0, fma4(u2.y, w1, fma4(u2.z, w2, fma4(u2.w, w3, a2))));
            a3 = fma4(u3.x, w0, fma4(u3.y, w1, fma4(u3.z, w2, fma4(u3.w, w3, a3))));
        }
        float4 accs[4] = {a0, a1, a2, a3};
#pragma unroll
        for (int r = 0; r < 4; ++r) {
            int row = row0 + rl + r;
            if (row < N_) {
                float4 a = accs[r];
                ushort4 o;
                o.x = f2bf(fmaxf(a.x + bb.x, 0.f));
                o.y = f2bf(fmaxf(a.y + bb.y, 0.f));
                o.z = f2bf(fmaxf(a.z + bb.z, 0.f));
                o.w = f2bf(fmaxf(a.w + bb.w, 0.f));
                ((ushort4*)hout)[(size_t)row * 32 + l] = o;
            }
        }
    }
}

// ---------------------------------------------------------------------------
// 7. Fused mu/logstd GEMM (columns interleaved); z = mu + noise*exp(ls), bf16.
// ---------------------------------------------------------------------------
__global__ __launch_bounds__(256, 2) void k_gemm_z(const float* __restrict__ g,
                                                   const float* __restrict__ Wmu,
                                                   const float* __restrict__ bmu,
                                                   const float* __restrict__ Wls,
                                                   const float* __restrict__ bls,
                                                   const float* __restrict__ noise,
                                                   unsigned int* __restrict__ z) {
    __shared__ float lw[D_ * D_];     // 64 KiB (interleaved Wmu|Wls)
    __shared__ float lu[32 * D_];     // 16 KiB
    int tid = threadIdx.x;
    for (int t = tid; t < D_ * 32; t += 256) {
        int k = t >> 5, j2 = t & 31;
        float2 m2 = ((const float2*)Wmu)[k * 32 + j2];
        float2 l2 = ((const float2*)Wls)[k * 32 + j2];
        ((float4*)lw)[t] = make_float4(m2.x, l2.x, m2.y, l2.y);
    }

    int l  = tid & 31;
    int rl = ((tid >> 6) << 3) + (((tid >> 5) & 1) << 2);
    float2 bm = ((const float2*)bmu)[l];
    float2 bl = ((const float2*)bls)[l];
    float4 bb = make_float4(bm.x, bl.x, bm.y, bl.y);

    for (int tile = blockIdx.x; tile * 32 < N_; tile += gridDim.x) {
        int row0 = tile * 32;
        __syncthreads();
#pragma unroll
        for (int i = 0; i < 4; ++i) {
            int flat = i * 256 + tid;
            int r = flat >> 5, c4 = flat & 31;
            int gr = row0 + r;
            ((float4*)lu)[flat] = (gr < N_) ? ((const float4*)g)[(size_t)gr * 32 + c4]
                                            : make_float4(0.f, 0.f, 0.f, 0.f);
        }
        __syncthreads();
        float4 a0 = {0,0,0,0}, a1 = {0,0,0,0}, a2 = {0,0,0,0}, a3 = {0,0,0,0};
#pragma unroll 4
        for (int k4 = 0; k4 < 32; ++k4) {
            int k = k4 * 4;
            float4 w0 = ((const float4*)(lw + (k + 0) * D_))[l];
            float4 w1 = ((const float4*)(lw + (k + 1) * D_))[l];
            float4 w2 = ((const float4*)(lw + (k + 2) * D_))[l];
            float4 w3 = ((const float4*)(lw + (k + 3) * D_))[l];
            float4 u0 = ((const float4*)(lu + (rl + 0) * D_))[k4];
            float4 u1 = ((const float4*)(lu + (rl + 1) * D_))[k4];
            float4 u2 = ((const float4*)(lu + (rl + 2) * D_))[k4];
            float4 u3 = ((const float4*)(lu + (rl + 3) * D_))[k4];
            a0 = fma4(u0.x, w0, fma4(u0.y, w1, fma4(u0.z, w2, fma4(u0.w, w3, a0))));
            a1 = fma4(u1.x, w0, fma4(u1.y, w1, fma4(u1.z, w2, fma4(u1.w, w3, a1))));
            a2 = fma4(u2.x, w0, fma4(u2.y, w1, fma4(u2.z, w2, fma4(u2.w, w3, a2))));
            a3 = fma4(u3.x, w0, fma4(u3.y, w1, fma4(u3.z, w2, fma4(u3.w, w3, a3))));
        }
        float4 accs[4] = {a0, a1, a2, a3};
#pragma unroll
        for (int r = 0; r < 4; ++r) {
            int row = row0 + rl + r;
            if (row < N_) {
                float4 a = accs[r];
                float2 n2 = ((const float2*)noise)[(size_t)row * 32 + l];
                float z0 = (a.x + bb.x) + n2.x * expf(a.y + bb.y);
                float z1 = (a.z + bb.z) + n2.y * expf(a.w + bb.w);
                z[(size_t)row * 32 + l] =
                    (unsigned int)f2bf(z0) | ((unsigned int)f2bf(z1) << 16);
            }
        }
    }
}

// ---------------------------------------------------------------------------
// 8. Decoder: logits[e] = dot(z[src], z[dst]) over 64 bf16. 16 lanes per edge.
// ---------------------------------------------------------------------------
__global__ __launch_bounds__(256) void k_decode(const int* __restrict__ src,
                                                const int* __restrict__ dst,
                                                const unsigned int* __restrict__ z,
                                                float* __restrict__ out) {
    int e = blockIdx.x * 16 + (threadIdx.x >> 4);
    if (e >= E_) return;
    int l = threadIdx.x & 15;
    int s = src[e], d = dst[e];
    uint2 za = ((const uint2*)z)[(size_t)s * 16 + l];
    uint2 zb = ((const uint2*)z)[(size_t)d * 16 + l];
    float p = blo(za.x) * blo(zb.x) + bhi(za.x) * bhi(zb.x)
            + blo(za.y) * blo(zb.y) + bhi(za.y) * bhi(zb.y);
#pragma unroll
    for (int o = 8; o; o >>= 1) p += __shfl_xor(p, o);
    if (l == 0) out[e] = p;
}

// ---------------------------------------------------------------------------
extern "C" void kernel_launch(void* const* d_in, const int* in_sizes, int n_in,
                              void* d_out, int out_size, void* d_ws, size_t ws_size,
                              hipStream_t stream) {
    const int*   fi    = (const int*)d_in[0];
    const float* fw    = (const float*)d_in[2];
    const int*   ei    = (const int*)d_in[3];
    const float* noise = (const float*)d_in[4];
    const float* emb   = (const float*)d_in[5];
    const float* W1    = (const float*)d_in[6];
    const float* b1    = (const float*)d_in[7];
    const float* Wmu   = (const float*)d_in[8];
    const float* bmu   = (const float*)d_in[9];
    const float* Wls   = (const float*)d_in[10];
    const float* bls   = (const float*)d_in[11];
    float* out = (float*)d_out;

    const int* src = ei;
    const int* dst = ei + E_;

    // Workspace layout (4-byte units)
    float*        ws        = (float*)d_ws;
    float*        agg       = ws;                                   // N*128 f32 (25.6MB)
    unsigned int* emb_bf    = (unsigned int*)agg;                   // V*64 u32 = 25.6MB, aliases agg
                                                                    // (dead before first k_gather)
    unsigned int* x         = (unsigned int*)(agg + (size_t)N_ * D_); // N*64 u32
    unsigned int* h         = x + (size_t)N_ * 64;                  // N*64 u32
    unsigned int* z         = h + (size_t)N_ * 64;                  // N*32 u32
    float*        disq      = (float*)(z + (size_t)N_ * 32);        // N
    float*        dinv      = disq + N_;                            // N
    int*          cnt       = (int*)(dinv + N_);                    // N
    int*          cursor    = cnt + N_;                             // N
    int*          row_start = cursor + N_;                          // N+1
    int*          sorted_src= row_start + (N_ + 1);                 // E

    hipMemsetAsync(cnt, 0, N_ * sizeof(int), stream);

    k_cvt    <<<(V_ * D_ / 8 + 255) / 256, 256, 0, stream>>>(emb, emb_bf);
    k_embed  <<<N_ / 4,            256, 0, stream>>>(fi, fw, emb_bf, x);
    k_degcnt <<<(E_ + 255) / 256,  256, 0, stream>>>(dst, cnt);
    k_degnorm<<<(N_ + 255) / 256,  256, 0, stream>>>(cnt, disq, dinv);
    k_scan   <<<1,                 256, 0, stream>>>(cnt, row_start, cursor);
    k_fill   <<<(E_ + 255) / 256,  256, 0, stream>>>(src, dst, cursor, sorted_src);

    // GCN layer 1
    k_gather   <<<N_ / 4, 256, 0, stream>>>(row_start, sorted_src, disq, dinv, x, agg);
    k_gemm_relu<<<512,    256, 0, stream>>>(agg, W1, b1, (unsigned short*)h);

    // GCN layers 2+3 (one gather of h, fused mu/ls GEMM)
    k_gather <<<N_ / 4,   256, 0, stream>>>(row_start, sorted_src, disq, dinv, h, agg);
    k_gemm_z <<<512,      256, 0, stream>>>(agg, Wmu, bmu, Wls, bls, noise, z);

    // Decoder
    k_decode <<<E_ / 16,  256, 0, stream>>>(src, dst, z, out);
}

// Round 5
// 540.929 us; speedup vs baseline: 1.3172x; 1.3172x over previous
//
#include <hip/hip_runtime.h>
#include <hip/hip_bf16.h>

// VGAE forward, MI355X. Gather-based GCN; bf16 storage for all gathered operands.
// CSR build via two-level binned counting sort (LDS cursors, no random 4B scatter).
constexpr int N_ = 50000;
constexpr int E_ = 1600000;
constexpr int D_ = 128;   // embedding_dim == hidden_dim
constexpr int O_ = 64;    // out_embedding_dim
constexpr int NNZ_ = 16;
constexpr int V_ = 100000;
constexpr int NBIN_ = (N_ + 255) / 256;   // 196 coarse bins (dst>>8)

static __device__ __forceinline__ unsigned short f2bf(float f) {
    __hip_bfloat16 h = __float2bfloat16(f);
    return __builtin_bit_cast(unsigned short, h);
}
static __device__ __forceinline__ float blo(unsigned int u) { return __uint_as_float(u << 16); }
static __device__ __forceinline__ float bhi(unsigned int u) { return __uint_as_float(u & 0xffff0000u); }
static __device__ __forceinline__ float4 fma4(float s, float4 a, float4 b) {
    return make_float4(fmaf(s, a.x, b.x), fmaf(s, a.y, b.y),
                       fmaf(s, a.z, b.z), fmaf(s, a.w, b.w));
}

// ---------------------------------------------------------------------------
// 0. Convert fp32 emb table [V][128] -> bf16 (packed u32 pairs).
// ---------------------------------------------------------------------------
__global__ __launch_bounds__(256) void k_cvt(const float* __restrict__ emb,
                                             unsigned int* __restrict__ emb_bf) {
    int t = blockIdx.x * blockDim.x + threadIdx.x;
    if (t >= V_ * D_ / 8) return;
    float4 a = ((const float4*)emb)[t * 2];
    float4 b = ((const float4*)emb)[t * 2 + 1];
    uint4 o;
    o.x = (unsigned int)f2bf(a.x) | ((unsigned int)f2bf(a.y) << 16);
    o.y = (unsigned int)f2bf(a.z) | ((unsigned int)f2bf(a.w) << 16);
    o.z = (unsigned int)f2bf(b.x) | ((unsigned int)f2bf(b.y) << 16);
    o.w = (unsigned int)f2bf(b.z) | ((unsigned int)f2bf(b.w) << 16);
    ((uint4*)emb_bf)[t] = o;
}

// ---------------------------------------------------------------------------
// 1. EmbeddingBag(sum) + L2 normalize from bf16 table. One wave per node.
// ---------------------------------------------------------------------------
__global__ __launch_bounds__(256) void k_embed(const int* __restrict__ fi,
                                               const float* __restrict__ fw,
                                               const unsigned int* __restrict__ emb_bf,
                                               unsigned int* __restrict__ x) {
    int n = blockIdx.x * 4 + (threadIdx.x >> 6);
    if (n >= N_) return;
    int lane = threadIdx.x & 63;
    float a0 = 0.f, a1 = 0.f;
    int base = n * NNZ_;
#pragma unroll
    for (int j = 0; j < NNZ_; ++j) {
        int idx  = fi[base + j];
        float w  = fw[base + j];
        unsigned int r = emb_bf[(size_t)idx * 64 + lane];
        a0 = fmaf(w, blo(r), a0);
        a1 = fmaf(w, bhi(r), a1);
    }
    float ss = a0 * a0 + a1 * a1;
#pragma unroll
    for (int o = 32; o; o >>= 1) ss += __shfl_xor(ss, o);
    float sc = 1.0f / fmaxf(sqrtf(ss), 1e-12f);
    x[(size_t)n * 64 + lane] =
        (unsigned int)f2bf(a0 * sc) | ((unsigned int)f2bf(a1 * sc) << 16);
}

// ---------------------------------------------------------------------------
// 2. In-degree histogram + normalization factors
// ---------------------------------------------------------------------------
__global__ __launch_bounds__(256) void k_degcnt(const int* __restrict__ dst,
                                                int* __restrict__ cnt) {
    int e = blockIdx.x * blockDim.x + threadIdx.x;
    if (e < E_) atomicAdd(&cnt[dst[e]], 1);
}

__global__ __launch_bounds__(256) void k_degnorm(const int* __restrict__ cnt,
                                                 float* __restrict__ disq,
                                                 float* __restrict__ dinv) {
    int n = blockIdx.x * blockDim.x + threadIdx.x;
    if (n < N_) {
        float deg = 1.0f + (float)cnt[n];
        disq[n] = rsqrtf(deg);
        dinv[n] = 1.0f / deg;
    }
}

// ---------------------------------------------------------------------------
// 3a. Per-coarse-bin edge-count: bsum[bin] = sum of cnt over its 256 nodes.
// ---------------------------------------------------------------------------
__global__ __launch_bounds__(256) void k_bsum(const int* __restrict__ cnt,
                                              int* __restrict__ bsum) {
    int t = threadIdx.x, n = (blockIdx.x << 8) + t;
    int v = (n < N_) ? cnt[n] : 0;
#pragma unroll
    for (int o = 32; o; o >>= 1) v += __shfl_xor(v, o);
    __shared__ int ws[4];
    if ((t & 63) == 0) ws[t >> 6] = v;
    __syncthreads();
    if (t == 0) bsum[blockIdx.x] = ws[0] + ws[1] + ws[2] + ws[3];
}

// ---------------------------------------------------------------------------
// 3b. Scan 196 bin counts -> coarse_start[197] (+ cursor copy); row_start[N]=E.
// ---------------------------------------------------------------------------
__global__ __launch_bounds__(256) void k_scan196(const int* __restrict__ bsum,
                                                 int* __restrict__ coarse_start,
                                                 int* __restrict__ coarse_cursor,
                                                 int* __restrict__ row_start) {
    __shared__ int s[256];
    int t = threadIdx.x;
    int v = (t < NBIN_) ? bsum[t] : 0;
    s[t] = v;
    __syncthreads();
    for (int o = 1; o < 256; o <<= 1) {
        int u = (t >= o) ? s[t - o] : 0;
        __syncthreads();
        s[t] += u;
        __syncthreads();
    }
    int excl = s[t] - v;
    if (t <= NBIN_) { coarse_start[t] = excl; coarse_cursor[t] = excl; }
    if (t == 0) row_start[N_] = E_;
}

// ---------------------------------------------------------------------------
// 3c. row_start: block-local exclusive scan of cnt + coarse_start offset.
// ---------------------------------------------------------------------------
__global__ __launch_bounds__(256) void k_rowstart(const int* __restrict__ cnt,
                                                  const int* __restrict__ coarse_start,
                                                  int* __restrict__ row_start) {
    __shared__ int s[256];
    int t = threadIdx.x, n = (blockIdx.x << 8) + t;
    int v = (n < N_) ? cnt[n] : 0;
    s[t] = v;
    __syncthreads();
    for (int o = 1; o < 256; o <<= 1) {
        int u = (t >= o) ? s[t - o] : 0;
        __syncthreads();
        s[t] += u;
        __syncthreads();
    }
    if (n < N_) row_start[n] = coarse_start[blockIdx.x] + (s[t] - v);
}

// ---------------------------------------------------------------------------
// 4a. Coarse binning: per-block LDS histogram over dst>>8; one global atomic
//     per (block,bin) reserves space; (src,dst) written grouped by bin.
// ---------------------------------------------------------------------------
constexpr int EPB_ = 4096;   // edges per block
__global__ __launch_bounds__(256) void k_bin(const int* __restrict__ src,
                                             const int* __restrict__ dst,
                                             int* __restrict__ coarse_cursor,
                                             uint2* __restrict__ binned) {
    __shared__ int hist[256], base[256];
    int t = threadIdx.x;
    int e0 = blockIdx.x * EPB_;
    hist[t] = 0;
    __syncthreads();
#pragma unroll
    for (int i = 0; i < EPB_ / 256; ++i) {
        int e = e0 + i * 256 + t;
        if (e < E_) atomicAdd(&hist[dst[e] >> 8], 1);
    }
    __syncthreads();
    if (t < NBIN_ && hist[t]) base[t] = atomicAdd(&coarse_cursor[t], hist[t]);
    __syncthreads();
#pragma unroll
    for (int i = 0; i < EPB_ / 256; ++i) {
        int e = e0 + i * 256 + t;
        if (e < E_) {
            int d = dst[e];
            int pos = atomicAdd(&base[d >> 8], 1);
            binned[pos] = make_uint2((unsigned int)src[e], (unsigned int)d);
        }
    }
}

// ---------------------------------------------------------------------------
// 4b. Final fill: one block per coarse bin; cursors in LDS; scatter lands in
//     a ~32KB window (L2-resident, lines fill completely).
// ---------------------------------------------------------------------------
__global__ __launch_bounds__(256) void k_fill2(const uint2* __restrict__ binned,
                                               const int* __restrict__ coarse_start,
                                               const int* __restrict__ row_start,
                                               int* __restrict__ sorted_src) {
    __shared__ int cur[256];
    int t = threadIdx.x;
    int n0 = blockIdx.x << 8;
    if (n0 + t < N_) cur[t] = row_start[n0 + t];
    __syncthreads();
    int beg = coarse_start[blockIdx.x], end = coarse_start[blockIdx.x + 1];
    for (int j = beg + t; j < end; j += 256) {
        uint2 e = binned[j];
        int pos = atomicAdd(&cur[e.y - (unsigned int)n0], 1);
        sorted_src[pos] = (int)e.x;
    }
}

// ---------------------------------------------------------------------------
// 5. Gather aggregation from bf16 rows:
//    agg[n] = disq[n] * sum_j disq[s_j]*v[s_j]  +  dinv[n]*v[n]
// ---------------------------------------------------------------------------
__global__ __launch_bounds__(256) void k_gather(const int* __restrict__ row_start,
                                                const int* __restrict__ sorted_src,
                                                const float* __restrict__ disq,
                                                const float* __restrict__ dinv,
                                                const unsigned int* __restrict__ v,
                                                float* __restrict__ agg) {
    int n = blockIdx.x * 4 + (threadIdx.x >> 6);
    if (n >= N_) return;
    int lane = threadIdx.x & 63;
    int beg = row_start[n], end = row_start[n + 1];
    float ax = 0.f, ay = 0.f;
    int j = beg;
    for (; j + 7 < end; j += 8) {
        int s0 = sorted_src[j],     s1 = sorted_src[j + 1];
        int s2 = sorted_src[j + 2], s3 = sorted_src[j + 3];
        int s4 = sorted_src[j + 4], s5 = sorted_src[j + 5];
        int s6 = sorted_src[j + 6], s7 = sorted_src[j + 7];
        float w0 = disq[s0], w1 = disq[s1], w2 = disq[s2], w3 = disq[s3];
        float w4 = disq[s4], w5 = disq[s5], w6 = disq[s6], w7 = disq[s7];
        unsigned int b0 = v[(size_t)s0 * 64 + lane];
        unsigned int b1 = v[(size_t)s1 * 64 + lane];
        unsigned int b2 = v[(size_t)s2 * 64 + lane];
        unsigned int b3 = v[(size_t)s3 * 64 + lane];
        unsigned int b4 = v[(size_t)s4 * 64 + lane];
        unsigned int b5 = v[(size_t)s5 * 64 + lane];
        unsigned int b6 = v[(size_t)s6 * 64 + lane];
        unsigned int b7 = v[(size_t)s7 * 64 + lane];
        ax = fmaf(w0, blo(b0), ax); ay = fmaf(w0, bhi(b0), ay);
        ax = fmaf(w1, blo(b1), ax); ay = fmaf(w1, bhi(b1), ay);
        ax = fmaf(w2, blo(b2), ax); ay = fmaf(w2, bhi(b2), ay);
        ax = fmaf(w3, blo(b3), ax); ay = fmaf(w3, bhi(b3), ay);
        ax = fmaf(w4, blo(b4), ax); ay = fmaf(w4, bhi(b4), ay);
        ax = fmaf(w5, blo(b5), ax); ay = fmaf(w5, bhi(b5), ay);
        ax = fmaf(w6, blo(b6), ax); ay = fmaf(w6, bhi(b6), ay);
        ax = fmaf(w7, blo(b7), ax); ay = fmaf(w7, bhi(b7), ay);
    }
    for (; j < end; ++j) {
        int s = sorted_src[j];
        float w = disq[s];
        unsigned int b = v[(size_t)s * 64 + lane];
        ax = fmaf(w, blo(b), ax); ay = fmaf(w, bhi(b), ay);
    }
    float dq = disq[n], di = dinv[n];
    unsigned int bs = v[(size_t)n * 64 + lane];
    ax = fmaf(di, blo(bs), ax * dq);
    ay = fmaf(di, bhi(bs), ay * dq);
    ((float2*)agg)[(size_t)n * 64 + lane] = make_float2(ax, ay);
}

// ---------------------------------------------------------------------------
// 6. Register-blocked GEMM: h = relu(agg @ W1 + b1), bf16 output.
// ---------------------------------------------------------------------------
__global__ __launch_bounds__(256, 2) void k_gemm_relu(const float* __restrict__ u,
                                                      const float* __restrict__ W,
                                                      const float* __restrict__ b,
                                                      unsigned short* __restrict__ hout) {
    __shared__ float lw[D_ * D_];     // 64 KiB
    __shared__ float lu[32 * D_];     // 16 KiB
    int tid = threadIdx.x;
    for (int t = tid; t < D_ * D_ / 4; t += 256)
        ((float4*)lw)[t] = ((const float4*)W)[t];

    int l  = tid & 31;
    int rl = ((tid >> 6) << 3) + (((tid >> 5) & 1) << 2);
    float4 bb = ((const float4*)b)[l];

    for (int tile = blockIdx.x; tile * 32 < N_; tile += gridDim.x) {
        int row0 = tile * 32;
        __syncthreads();
#pragma unroll
        for (int i = 0; i < 4; ++i) {
            int flat = i * 256 + tid;
            int r = flat >> 5, c4 = flat & 31;
            int gr = row0 + r;
            ((float4*)lu)[flat] = (gr < N_) ? ((const float4*)u)[(size_t)gr * 32 + c4]
                                            : make_float4(0.f, 0.f, 0.f, 0.f);
        }
        __syncthreads();
        float4 a0 = {0,0,0,0}, a1 = {0,0,0,0}, a2 = {0,0,0,0}, a3 = {0,0,0,0};
#pragma unroll 4
        for (int k4 = 0; k4 < 32; ++k4) {
            int k = k4 * 4;
            float4 w0 = ((const float4*)(lw + (k + 0) * D_))[l];
            float4 w1 = ((const float4*)(lw + (k + 1) * D_))[l];
            float4 w2 = ((const float4*)(lw + (k + 2) * D_))[l];
            float4 w3 = ((const float4*)(lw + (k + 3) * D_))[l];
            float4 u0 = ((const float4*)(lu + (rl + 0) * D_))[k4];
            float4 u1 = ((const float4*)(lu + (rl + 1) * D_))[k4];
            float4 u2 = ((const float4*)(lu + (rl + 2) * D_))[k4];
            float4 u3 = ((const float4*)(lu + (rl + 3) * D_))[k4];
            a0 = fma4(u0.x, w0, fma4(u0.y, w1, fma4(u0.z, w2, fma4(u0.w, w3, a0))));
            a1 = fma4(u1.x, w0, fma4(u1.y, w1, fma4(u1.z, w2, fma4(u1.w, w3, a1))));
            a2 = fma4(u2.x, w0, fma4(u2.y, w1, fma4(u2.z, w2, fma4(u2.w, w3, a2))));
            a3 = fma4(u3.x, w0, fma4(u3.y, w1, fma4(u3.z, w2, fma4(u3.w, w3, a3))));
        }
        float4 accs[4] = {a0, a1, a2, a3};
#pragma unroll
        for (int r = 0; r < 4; ++r) {
            int row = row0 + rl + r;
            if (row < N_) {
                float4 a = accs[r];
                ushort4 o;
                o.x = f2bf(fmaxf(a.x + bb.x, 0.f));
                o.y = f2bf(fmaxf(a.y + bb.y, 0.f));
                o.z = f2bf(fmaxf(a.z + bb.z, 0.f));
                o.w = f2bf(fmaxf(a.w + bb.w, 0.f));
                ((ushort4*)hout)[(size_t)row * 32 + l] = o;
            }
        }
    }
}

// ---------------------------------------------------------------------------
// 7. Fused mu/logstd GEMM (columns interleaved); z = mu + noise*exp(ls), bf16.
// ---------------------------------------------------------------------------
__global__ __launch_bounds__(256, 2) void k_gemm_z(const float* __restrict__ g,
                                                   const float* __restrict__ Wmu,
                                                   const float* __restrict__ bmu,
                                                   const float* __restrict__ Wls,
                                                   const float* __restrict__ bls,
                                                   const float* __restrict__ noise,
                                                   unsigned int* __restrict__ z) {
    __shared__ float lw[D_ * D_];     // 64 KiB (interleaved Wmu|Wls)
    __shared__ float lu[32 * D_];     // 16 KiB
    int tid = threadIdx.x;
    for (int t = tid; t < D_ * 32; t += 256) {
        int k = t >> 5, j2 = t & 31;
        float2 m2 = ((const float2*)Wmu)[k * 32 + j2];
        float2 l2 = ((const float2*)Wls)[k * 32 + j2];
        ((float4*)lw)[t] = make_float4(m2.x, l2.x, m2.y, l2.y);
    }

    int l  = tid & 31;
    int rl = ((tid >> 6) << 3) + (((tid >> 5) & 1) << 2);
    float2 bm = ((const float2*)bmu)[l];
    float2 bl = ((const float2*)bls)[l];
    float4 bb = make_float4(bm.x, bl.x, bm.y, bl.y);

    for (int tile = blockIdx.x; tile * 32 < N_; tile += gridDim.x) {
        int row0 = tile * 32;
        __syncthreads();
#pragma unroll
        for (int i = 0; i < 4; ++i) {
            int flat = i * 256 + tid;
            int r = flat >> 5, c4 = flat & 31;
            int gr = row0 + r;
            ((float4*)lu)[flat] = (gr < N_) ? ((const float4*)g)[(size_t)gr * 32 + c4]
                                            : make_float4(0.f, 0.f, 0.f, 0.f);
        }
        __syncthreads();
        float4 a0 = {0,0,0,0}, a1 = {0,0,0,0}, a2 = {0,0,0,0}, a3 = {0,0,0,0};
#pragma unroll 4
        for (int k4 = 0; k4 < 32; ++k4) {
            int k = k4 * 4;
            float4 w0 = ((const float4*)(lw + (k + 0) * D_))[l];
            float4 w1 = ((const float4*)(lw + (k + 1) * D_))[l];
            float4 w2 = ((const float4*)(lw + (k + 2) * D_))[l];
            float4 w3 = ((const float4*)(lw + (k + 3) * D_))[l];
            float4 u0 = ((const float4*)(lu + (rl + 0) * D_))[k4];
            float4 u1 = ((const float4*)(lu + (rl + 1) * D_))[k4];
            float4 u2 = ((const float4*)(lu + (rl + 2) * D_))[k4];
            float4 u3 = ((const float4*)(lu + (rl + 3) * D_))[k4];
            a0 = fma4(u0.x, w0, fma4(u0.y, w1, fma4(u0.z, w2, fma4(u0.w, w3, a0))));
            a1 = fma4(u1.x, w0, fma4(u1.y, w1, fma4(u1.z, w2, fma4(u1.w, w3, a1))));
            a2 = fma4(u2.x, w0, fma4(u2.y, w1, fma4(u2.z, w2, fma4(u2.w, w3, a2))));
            a3 = fma4(u3.x, w0, fma4(u3.y, w1, fma4(u3.z, w2, fma4(u3.w, w3, a3))));
        }
        float4 accs[4] = {a0, a1, a2, a3};
#pragma unroll
        for (int r = 0; r < 4; ++r) {
            int row = row0 + rl + r;
            if (row < N_) {
                float4 a = accs[r];
                float2 n2 = ((const float2*)noise)[(size_t)row * 32 + l];
                float z0 = (a.x + bb.x) + n2.x * expf(a.y + bb.y);
                float z1 = (a.z + bb.z) + n2.y * expf(a.w + bb.w);
                z[(size_t)row * 32 + l] =
                    (unsigned int)f2bf(z0) | ((unsigned int)f2bf(z1) << 16);
            }
        }
    }
}

// ---------------------------------------------------------------------------
// 8. Decoder: logits[e] = dot(z[src], z[dst]) over 64 bf16. 16 lanes per edge.
// ---------------------------------------------------------------------------
__global__ __launch_bounds__(256) void k_decode(const int* __restrict__ src,
                                                const int* __restrict__ dst,
                                                const unsigned int* __restrict__ z,
                                                float* __restrict__ out) {
    int e = blockIdx.x * 16 + (threadIdx.x >> 4);
    if (e >= E_) return;
    int l = threadIdx.x & 15;
    int s = src[e], d = dst[e];
    uint2 za = ((const uint2*)z)[(size_t)s * 16 + l];
    uint2 zb = ((const uint2*)z)[(size_t)d * 16 + l];
    float p = blo(za.x) * blo(zb.x) + bhi(za.x) * bhi(zb.x)
            + blo(za.y) * blo(zb.y) + bhi(za.y) * bhi(zb.y);
#pragma unroll
    for (int o = 8; o; o >>= 1) p += __shfl_xor(p, o);
    if (l == 0) out[e] = p;
}

// ---------------------------------------------------------------------------
extern "C" void kernel_launch(void* const* d_in, const int* in_sizes, int n_in,
                              void* d_out, int out_size, void* d_ws, size_t ws_size,
                              hipStream_t stream) {
    const int*   fi    = (const int*)d_in[0];
    const float* fw    = (const float*)d_in[2];
    const int*   ei    = (const int*)d_in[3];
    const float* noise = (const float*)d_in[4];
    const float* emb   = (const float*)d_in[5];
    const float* W1    = (const float*)d_in[6];
    const float* b1    = (const float*)d_in[7];
    const float* Wmu   = (const float*)d_in[8];
    const float* bmu   = (const float*)d_in[9];
    const float* Wls   = (const float*)d_in[10];
    const float* bls   = (const float*)d_in[11];
    float* out = (float*)d_out;

    const int* src = ei;
    const int* dst = ei + E_;

    // Workspace layout (4-byte units). The 25.6MB "alias" region serves, in
    // non-overlapping lifetime order: emb_bf (cvt->embed), binned (bin->fill2),
    // agg (gather->gemm).
    float*        ws        = (float*)d_ws;
    float*        agg       = ws;                                    // N*128 f32 = 25.6MB
    unsigned int* emb_bf    = (unsigned int*)agg;                    // V*64 u32 = 25.6MB
    uint2*        binned    = (uint2*)agg;                           // E uint2 = 12.8MB
    unsigned int* x         = (unsigned int*)(agg + (size_t)N_ * D_);// N*64 u32
    unsigned int* h         = x + (size_t)N_ * 64;                   // N*64 u32
    unsigned int* z         = h + (size_t)N_ * 64;                   // N*32 u32
    float*        disq      = (float*)(z + (size_t)N_ * 32);         // N
    float*        dinv      = disq + N_;                             // N
    int*          cnt       = (int*)(dinv + N_);                     // N
    int*          row_start = cnt + N_;                              // N+1
    int*          sorted_src= row_start + (N_ + 1);                  // E
    int*          bsum      = sorted_src + E_;                       // NBIN
    int*          coarse_start  = bsum + 256;                        // NBIN+1
    int*          coarse_cursor = coarse_start + 256;                // NBIN+1

    hipMemsetAsync(cnt, 0, N_ * sizeof(int), stream);

    k_cvt    <<<(V_ * D_ / 8 + 255) / 256, 256, 0, stream>>>(emb, emb_bf);
    k_embed  <<<N_ / 4,            256, 0, stream>>>(fi, fw, emb_bf, x);
    k_degcnt <<<(E_ + 255) / 256,  256, 0, stream>>>(dst, cnt);
    k_degnorm<<<(N_ + 255) / 256,  256, 0, stream>>>(cnt, disq, dinv);
    k_bsum   <<<NBIN_,             256, 0, stream>>>(cnt, bsum);
    k_scan196<<<1,                 256, 0, stream>>>(bsum, coarse_start, coarse_cursor,
                                                     row_start);
    k_rowstart<<<NBIN_,            256, 0, stream>>>(cnt, coarse_start, row_start);
    k_bin    <<<(E_ + EPB_ - 1) / EPB_, 256, 0, stream>>>(src, dst, coarse_cursor, binned);
    k_fill2  <<<NBIN_,             256, 0, stream>>>(binned, coarse_start, row_start,
                                                     sorted_src);

    // GCN layer 1
    k_gather   <<<N_ / 4, 256, 0, stream>>>(row_start, sorted_src, disq, dinv, x, agg);
    k_gemm_relu<<<512,    256, 0, stream>>>(agg, W1, b1, (unsigned short*)h);

    // GCN layers 2+3 (one gather of h, fused mu/ls GEMM)
    k_gather <<<N_ / 4,   256, 0, stream>>>(row_start, sorted_src, disq, dinv, h, agg);
    k_gemm_z <<<512,      256, 0, stream>>>(agg, Wmu, bmu, Wls, bls, noise, z);

    // Decoder
    k_decode <<<E_ / 16,  256, 0, stream>>>(src, dst, z, out);
}